// Round 5
// baseline (1340.769 us; speedup 1.0000x reference)
//
#include <hip/hip_runtime.h>
#include <math.h>

#define T_STEPS 8192

// hardware transcendentals (v_exp_f32 = 2^x, v_log_f32 = log2 x)
__device__ __forceinline__ float hw_exp2(float x) { return __builtin_amdgcn_exp2f(x); }
__device__ __forceinline__ float hw_log2(float x) { return __builtin_amdgcn_logf(x); }

// DPP add of rotated copy within 16-lane rows. CTRL = 0x120|n (row_ror:n).
template<int CTRL>
__device__ __forceinline__ float dpp_add(float x) {
    int y = __builtin_amdgcn_update_dpp(0, __float_as_int(x), CTRL, 0xF, 0xF, true);
    return x + __int_as_float(y);
}
__device__ __forceinline__ float row16_sum(float x) {
    x = dpp_add<0x128>(x);   // ror:8
    x = dpp_add<0x124>(x);   // ror:4
    x = dpp_add<0x122>(x);   // ror:2
    x = dpp_add<0x121>(x);   // ror:1
    return x;
}

// ---------------------------------------------------------------------------
// Pass B: snow + upper bucket. One thread per (ensemble, band).
// 16 blocks x 64 threads. Outputs per (e,t): rech = sum af*perc (to ws) and
// qs = sum af*(qsurf+qif) (to d_out). No s2 work here: the DPP reductions
// feed only stores, so the per-step critical path is just the s1 chain.
// ---------------------------------------------------------------------------
__global__ __launch_bounds__(64) void fuse_upper_kernel(
    const float* __restrict__ raw,        // [64][29]
    const float* __restrict__ forcing,    // [8192][3]
    const float* __restrict__ state_init, // [2]
    const float* __restrict__ area_frac,  // [16]
    const float* __restrict__ mean_elev,  // [16]
    float* __restrict__ rech_out,         // ws: [64][8192]
    float* __restrict__ qs_out)           // d_out: [64][8192]
{
    const int lane = threadIdx.x;   // 0..63
    const int grp  = lane >> 4;     // ensemble within wave
    const int nb   = lane & 15;     // band
    const int e    = blockIdx.x * 4 + grp;

    const float* rp = raw + e * 29;
    auto phys = [&](int idx, float lo, float hi) {
        float x = rp[idx];
        float s = 1.0f / (1.0f + expf(-x));
        return lo + (hi - lo) * s;
    };
    const float s1max = phys(0,  50.0f,  5000.0f);
    const float ku    = phys(6,  0.01f,  1000.0f);
    const float c_exp = phys(7,  1.0f,   20.0f);
    const float ki    = phys(11, 0.01f,  1000.0f);
    const float acmax = phys(17, 0.05f,  0.95f);
    const float b_exp = phys(18, 0.001f, 3.0f);
    const float train = phys(22, -2.0f,  4.0f);
    const float tmelt = phys(23, -2.0f,  4.0f);
    const float mrate = phys(24, 1.0f,   10.0f);
    const float lapse = phys(25, -9.8f,  0.0f);
    const float opg   = phys(26, 0.0f,   1.0f);

    const float delev  = (mean_elev[nb] - 1500.0f) / 1000.0f;  // match ref /1000
    const float tshift = lapse * delev;
    const float pmult  = fmaxf(1.0f + opg * delev, 0.0f);
    const float af     = area_frac[nb];
    const float inv_s1max = 1.0f / s1max;

    float swe = 0.0f;
    float s1  = state_init[0];   // invariant: s1 in [0, s1max]
    float rkeep = 0.0f, qkeep = 0.0f;

    float* __restrict__ rout = rech_out + (size_t)e * T_STEPS;
    float* __restrict__ qout = qs_out   + (size_t)e * T_STEPS;

    // prefetch steps 0..3 of forcing
    float4 c0 = *(const float4*)(forcing + 0);
    float4 c1 = *(const float4*)(forcing + 4);
    float4 c2 = *(const float4*)(forcing + 8);

    for (int t0 = 0; t0 < T_STEPS; t0 += 16) {
        #pragma unroll
        for (int tt = 0; tt < 16; tt += 4) {
            int tn = t0 + tt + 4;
            tn = (tn > T_STEPS - 4) ? (T_STEPS - 4) : tn;
            const float4 n0 = *(const float4*)(forcing + 3 * tn);
            const float4 n1 = *(const float4*)(forcing + 3 * tn + 4);
            const float4 n2 = *(const float4*)(forcing + 3 * tn + 8);

            const float P [4] = { c0.x, c0.w, c1.z, c2.y };
            const float PE[4] = { c0.y, c1.x, c1.w, c2.z };
            const float TA[4] = { c0.z, c1.y, c2.x, c2.w };

            #pragma unroll
            for (int k = 0; k < 4; ++k) {
                const float p = P[k], pet = PE[k], tair = TA[k];

                // snow bucket (branch math kept bit-identical to reference)
                const float tb   = tair + tshift;
                const float pb   = p * pmult;
                const float snow = (tb > train) ? 0.0f : pb;     // pb - rain
                const float ssn  = swe + snow;
                const float mcap = mrate * fmaxf(tb - tmelt, 0.0f);
                const float swen = fmaxf(ssn - mcap, 0.0f);
                const float infl = pb + swe - swen;              // rain + melt
                swe = swen;

                // upper bucket (w1 in [0,1] by invariant)
                const float w1   = s1 * inv_s1max;
                const float lg   = hw_log2(w1);
                const float pwb  = hw_exp2(b_exp * lg);   // w1^b
                const float pwc  = hw_exp2(c_exp * lg);   // w1^c
                const float perc = ku * pwc;
                const float qif  = ki * w1;
                const float qsx  = (acmax * infl) * pwb;
                const float s1n  = s1 + infl - qsx - pet * w1 - perc - qif;
                const float sHi  = fminf(s1n, s1max);
                const float over1 = s1n - sHi;
                s1 = fmaxf(sHi, 0.0f);
                const float qsurf = qsx + over1;

                // per-ensemble band sums (pure stores, off the critical path)
                const float r1 = row16_sum(af * perc);
                const float r2 = row16_sum(af * (qsurf + qif));

                const bool sel = ((tt + k) == nb);
                rkeep = sel ? r1 : rkeep;
                qkeep = sel ? r2 : qkeep;
            }
            c0 = n0; c1 = n1; c2 = n2;
        }
        // one coalesced store per array per 16 steps
        rout[t0 + nb] = rkeep;
        qout[t0 + nb] = qkeep;
    }
}

// ---------------------------------------------------------------------------
// Pass C: lower bucket. ONE wave; lane = ensemble. Reads rech (ws) and
// qs (d_out), writes q in place into d_out. float4 chunks, 2-deep prefetch.
// ---------------------------------------------------------------------------
__global__ __launch_bounds__(64) void fuse_lower_kernel(
    const float* __restrict__ raw,        // [64][29]
    const float* __restrict__ state_init, // [2]
    const float* __restrict__ rech,       // ws: [64][8192]
    float* __restrict__ q_io)             // d_out: in = qs, out = q
{
    const int e = threadIdx.x;  // 0..63

    const float* rp = raw + e * 29;
    auto phys = [&](int idx, float lo, float hi) {
        float x = rp[idx];
        float s = 1.0f / (1.0f + expf(-x));
        return lo + (hi - lo) * s;
    };
    const float s2max = phys(1,  100.0f, 10000.0f);
    const float ks    = phys(12, 0.001f, 10000.0f);
    const float n_exp = phys(13, 1.0f,   10.0f);
    const float inv_s2max = 1.0f / s2max;

    float s2 = state_init[1];   // 250; invariant s2 >= 0 after clamps

    const float4* rv = (const float4*)(rech + (size_t)e * T_STEPS);
    float4*       qv = (float4*)(q_io + (size_t)e * T_STEPS);

    const int NC = T_STEPS / 4;   // 2048 chunks
    float4 r0 = rv[0], r1 = rv[1];
    float4 q0 = qv[0], q1 = qv[1];

    for (int c = 0; c < NC; ++c) {
        const int cn = (c + 2 < NC) ? (c + 2) : (NC - 1);
        const float4 rn = rv[cn];
        const float4 qn = qv[cn];

        const float R[4] = { r0.x, r0.y, r0.z, r0.w };
        const float S[4] = { q0.x, q0.y, q0.z, q0.w };
        float O[4];

        #pragma unroll
        for (int k = 0; k < 4; ++k) {
            const float w2   = fminf(s2 * inv_s2max, 1.0f);
            const float qb   = ks * hw_exp2(n_exp * hw_log2(w2));
            const float s2n  = s2 + R[k] - qb;
            const float sHi  = fminf(s2n, s2max);
            const float over2 = s2n - sHi;
            s2 = fmaxf(sHi, 0.0f);
            O[k] = S[k] + qb + over2;
        }
        qv[c] = make_float4(O[0], O[1], O[2], O[3]);

        r0 = r1; r1 = rn;
        q0 = q1; q1 = qn;
    }
}

// ---------------------------------------------------------------------------
// Route: gamma unit-hydrograph, 30-tap causal FIR along time. In-place on
// d_out (full row staged in LDS before any write).
// ---------------------------------------------------------------------------
__global__ __launch_bounds__(256) void route_kernel(
    const float* __restrict__ raw,     // [64][29]
    float* __restrict__ q_io)          // d_out: in = q, out = routed
{
    __shared__ float w_sh[32];
    __shared__ float row[T_STEPS];     // 32 KB

    const int e   = blockIdx.x;
    const int tid = threadIdx.x;

    const float4* src  = (const float4*)(q_io + (size_t)e * T_STEPS);
    float4*       dst4 = (float4*)row;
    for (int i = tid; i < T_STEPS / 4; i += 256) dst4[i] = src[i];

    if (tid < 32) {
        float x     = raw[e * 29 + 21];                 // mu_t raw
        float sig   = 1.0f / (1.0f + expf(-x));
        float delay = 0.01f + (5.0f - 0.01f) * sig;
        float wv = 0.0f;
        if (tid < 30) {
            const float tm   = (float)tid + 0.5f;
            const float kk   = 2.5f;
            const float lgam = 0.28468287047291918f;    // lgamma(2.5)
            float lp = (kk - 1.0f) * logf(tm) - tm / delay - lgam - kk * logf(delay);
            wv = expf(lp);
        }
        w_sh[tid] = wv;
    }
    __syncthreads();
    if (tid == 0) {
        float s = 0.0f;
        for (int l = 0; l < 30; ++l) s += w_sh[l];
        w_sh[31] = 1.0f / s;
    }
    __syncthreads();

    float wloc[30];
    const float inv = w_sh[31];
    #pragma unroll
    for (int l = 0; l < 30; ++l) wloc[l] = w_sh[l] * inv;

    float* __restrict__ out = q_io + (size_t)e * T_STEPS;
    for (int t = tid; t < T_STEPS; t += 256) {
        float acc = 0.0f;
        #pragma unroll
        for (int l = 0; l < 30; ++l) {
            const int idx = t - l;
            const float v = (idx >= 0) ? row[idx] : 0.0f;
            acc = fmaf(wloc[l], v, acc);
        }
        out[t] = acc;
    }
}

// ---------------------------------------------------------------------------
extern "C" void kernel_launch(void* const* d_in, const int* in_sizes, int n_in,
                              void* d_out, int out_size, void* d_ws, size_t ws_size,
                              hipStream_t stream) {
    const float* raw        = (const float*)d_in[0];   // (64, 29)
    const float* forcing    = (const float*)d_in[1];   // (8192, 3)
    const float* state_init = (const float*)d_in[2];   // (2,)
    const float* area_frac  = (const float*)d_in[3];   // (16,)
    const float* mean_elev  = (const float*)d_in[4];   // (16,)

    float* out  = (float*)d_out;                       // (64, 8192)
    float* rech = (float*)d_ws;                        // 2 MB scratch

    fuse_upper_kernel<<<16, 64, 0, stream>>>(raw, forcing, state_init,
                                             area_frac, mean_elev, rech, out);
    fuse_lower_kernel<<<1, 64, 0, stream>>>(raw, state_init, rech, out);
    route_kernel<<<64, 256, 0, stream>>>(raw, out);
}

// Round 6
// 1027.150 us; speedup vs baseline: 1.3053x; 1.3053x over previous
//
#include <hip/hip_runtime.h>
#include <math.h>

#define T_STEPS 8192

// hardware transcendentals (v_exp_f32 = 2^x, v_log_f32 = log2 x)
__device__ __forceinline__ float hw_exp2(float x) { return __builtin_amdgcn_exp2f(x); }
__device__ __forceinline__ float hw_log2(float x) { return __builtin_amdgcn_logf(x); }

// DPP add of rotated copy within 16-lane rows. CTRL = 0x120|n (row_ror:n).
template<int CTRL>
__device__ __forceinline__ float dpp_add(float x) {
    int y = __builtin_amdgcn_update_dpp(0, __float_as_int(x), CTRL, 0xF, 0xF, true);
    return x + __int_as_float(y);
}
__device__ __forceinline__ float row16_sum(float x) {
    x = dpp_add<0x128>(x);   // ror:8
    x = dpp_add<0x124>(x);   // ror:4
    x = dpp_add<0x122>(x);   // ror:2
    x = dpp_add<0x121>(x);   // ror:1
    return x;
}

// ---------------------------------------------------------------------------
// Fused FUSE scan. One thread per (ensemble, band); 16 blocks x 64 threads.
// __launch_bounds__(64, 1): 1 wave/EU minimum -> RA may use up to ~512 VGPRs.
// (R5 post-mortem: default bounds gave VGPR_Count=32, serializing the whole
// unrolled body behind register reuse; we only ever have 1 wave per CU, so
// occupancy is worthless here and registers are free.)
// ---------------------------------------------------------------------------
__global__ __launch_bounds__(64, 1) void fuse_scan_kernel(
    const float* __restrict__ raw,        // [64][29]
    const float* __restrict__ forcing,    // [8192][3]
    const float* __restrict__ state_init, // [2]
    const float* __restrict__ area_frac,  // [16]
    const float* __restrict__ mean_elev,  // [16]
    float* __restrict__ qout)             // d_out: [64][8192]
{
    const int lane = threadIdx.x;   // 0..63
    const int grp  = lane >> 4;     // ensemble within wave
    const int nb   = lane & 15;     // band
    const int e    = blockIdx.x * 4 + grp;

    const float* rp = raw + e * 29;
    auto phys = [&](int idx, float lo, float hi) {
        float x = rp[idx];
        float s = 1.0f / (1.0f + expf(-x));
        return lo + (hi - lo) * s;
    };
    const float s1max = phys(0,  50.0f,  5000.0f);
    const float s2max = phys(1,  100.0f, 10000.0f);
    const float ku    = phys(6,  0.01f,  1000.0f);
    const float c_exp = phys(7,  1.0f,   20.0f);
    const float ki    = phys(11, 0.01f,  1000.0f);
    const float ks    = phys(12, 0.001f, 10000.0f);
    const float n_exp = phys(13, 1.0f,   10.0f);
    const float acmax = phys(17, 0.05f,  0.95f);
    const float b_exp = phys(18, 0.001f, 3.0f);
    const float train = phys(22, -2.0f,  4.0f);
    const float tmelt = phys(23, -2.0f,  4.0f);
    const float mrate = phys(24, 1.0f,   10.0f);
    const float lapse = phys(25, -9.8f,  0.0f);
    const float opg   = phys(26, 0.0f,   1.0f);

    const float delev  = (mean_elev[nb] - 1500.0f) / 1000.0f;
    const float tshift = lapse * delev;
    const float pmult  = fmaxf(1.0f + opg * delev, 0.0f);
    const float af     = area_frac[nb];
    const float inv_s1max = 1.0f / s1max;
    const float inv_s2max = 1.0f / s2max;

    float swe = 0.0f;
    float s1  = state_init[0];   // invariant: s1 in [0, s1max]
    float s2  = state_init[1];   // 250; invariant s2 >= 0 after first clamp
    float qkeep = 0.0f;

    float* __restrict__ out = qout + (size_t)e * T_STEPS;
    const float4* __restrict__ fvec = (const float4*)forcing;  // 12 float4 / 16 steps

    // double-buffered forcing group (16 steps = 48 floats = 12 float4)
    float fc[48], fn[48];
    {
        #pragma unroll
        for (int i = 0; i < 12; ++i) {
            const float4 L = fvec[i];
            fc[4*i+0] = L.x; fc[4*i+1] = L.y; fc[4*i+2] = L.z; fc[4*i+3] = L.w;
        }
    }

    for (int t0 = 0; t0 < T_STEPS; t0 += 16) {
        // prefetch next group's forcing (clamped at tail)
        const int g_next = (t0 + 16 < T_STEPS) ? (t0 + 16) : t0;
        const int base   = (g_next >> 4) * 12;
        #pragma unroll
        for (int i = 0; i < 12; ++i) {
            const float4 L = fvec[base + i];
            fn[4*i+0] = L.x; fn[4*i+1] = L.y; fn[4*i+2] = L.z; fn[4*i+3] = L.w;
        }

        #pragma unroll
        for (int tt = 0; tt < 16; ++tt) {
            const float p    = fc[3*tt + 0];
            const float pet  = fc[3*tt + 1];
            const float tair = fc[3*tt + 2];

            // snow bucket (branchless; algebraically identical to reference)
            const float tb   = tair + tshift;
            const float pb   = p * pmult;
            const float snow = (tb > train) ? 0.0f : pb;
            const float ssn  = swe + snow;
            const float mcap = mrate * fmaxf(tb - tmelt, 0.0f);
            const float swen = fmaxf(ssn - mcap, 0.0f);
            const float infl = pb + swe - swen;              // rain + melt
            swe = swen;

            // upper bucket (w1 in [0,1] by invariant; log2(0)->-inf -> pow=0)
            const float w1   = s1 * inv_s1max;
            const float lg   = hw_log2(w1);
            const float pwb  = hw_exp2(b_exp * lg);          // w1^b
            const float pwc  = hw_exp2(c_exp * lg);          // w1^c
            const float perc = ku * pwc;
            const float qif  = ki * w1;
            const float qsx  = (acmax * infl) * pwb;
            const float s1n  = (s1 + infl) - ((qsx + pet * w1) + (perc + qif));
            const float sHi  = fminf(s1n, s1max);
            const float over1 = s1n - sHi;
            s1 = fmaxf(sHi, 0.0f);
            const float qsurf = qsx + over1;

            // per-ensemble band sums (16-lane DPP butterflies)
            const float r1 = row16_sum(af * perc);           // rech
            const float r2 = row16_sum(af * (qsurf + qif));  // surface q

            // lower bucket (replicated identically across the 16-lane row;
            // qb depends only on s2, so it runs parallel to the DPP chain)
            const float w2   = fminf(s2 * inv_s2max, 1.0f);
            const float qb   = ks * hw_exp2(n_exp * hw_log2(w2));
            const float s2n  = s2 + r1 - qb;
            const float s2Hi = fminf(s2n, s2max);
            const float over2 = s2n - s2Hi;
            s2 = fmaxf(s2Hi, 0.0f);

            const float q = r2 + qb + over2;
            qkeep = (tt == nb) ? q : qkeep;                  // lane nb keeps step t0+nb
        }

        // one coalesced store per 16 steps
        out[t0 + nb] = qkeep;

        #pragma unroll
        for (int i = 0; i < 48; ++i) fc[i] = fn[i];
    }
}

// ---------------------------------------------------------------------------
// Route: gamma unit-hydrograph, 30-tap causal FIR along time. In-place on
// d_out (full row staged in LDS before any write).
// ---------------------------------------------------------------------------
__global__ __launch_bounds__(256) void route_kernel(
    const float* __restrict__ raw,     // [64][29]
    float* __restrict__ q_io)          // d_out: in = q, out = routed
{
    __shared__ float w_sh[32];
    __shared__ float row[T_STEPS];     // 32 KB

    const int e   = blockIdx.x;
    const int tid = threadIdx.x;

    const float4* src  = (const float4*)(q_io + (size_t)e * T_STEPS);
    float4*       dst4 = (float4*)row;
    for (int i = tid; i < T_STEPS / 4; i += 256) dst4[i] = src[i];

    if (tid < 32) {
        float x     = raw[e * 29 + 21];                 // mu_t raw
        float sig   = 1.0f / (1.0f + expf(-x));
        float delay = 0.01f + (5.0f - 0.01f) * sig;
        float wv = 0.0f;
        if (tid < 30) {
            const float tm   = (float)tid + 0.5f;
            const float kk   = 2.5f;
            const float lgam = 0.28468287047291918f;    // lgamma(2.5)
            float lp = (kk - 1.0f) * logf(tm) - tm / delay - lgam - kk * logf(delay);
            wv = expf(lp);
        }
        w_sh[tid] = wv;
    }
    __syncthreads();
    if (tid == 0) {
        float s = 0.0f;
        for (int l = 0; l < 30; ++l) s += w_sh[l];
        w_sh[31] = 1.0f / s;
    }
    __syncthreads();

    float wloc[30];
    const float inv = w_sh[31];
    #pragma unroll
    for (int l = 0; l < 30; ++l) wloc[l] = w_sh[l] * inv;

    float* __restrict__ out = q_io + (size_t)e * T_STEPS;
    for (int t = tid; t < T_STEPS; t += 256) {
        float acc = 0.0f;
        #pragma unroll
        for (int l = 0; l < 30; ++l) {
            const int idx = t - l;
            const float v = (idx >= 0) ? row[idx] : 0.0f;
            acc = fmaf(wloc[l], v, acc);
        }
        out[t] = acc;
    }
}

// ---------------------------------------------------------------------------
extern "C" void kernel_launch(void* const* d_in, const int* in_sizes, int n_in,
                              void* d_out, int out_size, void* d_ws, size_t ws_size,
                              hipStream_t stream) {
    const float* raw        = (const float*)d_in[0];   // (64, 29)
    const float* forcing    = (const float*)d_in[1];   // (8192, 3)
    const float* state_init = (const float*)d_in[2];   // (2,)
    const float* area_frac  = (const float*)d_in[3];   // (16,)
    const float* mean_elev  = (const float*)d_in[4];   // (16,)

    float* out = (float*)d_out;                        // (64, 8192)

    fuse_scan_kernel<<<16, 64, 0, stream>>>(raw, forcing, state_init,
                                            area_frac, mean_elev, out);
    route_kernel<<<64, 256, 0, stream>>>(raw, out);
}

// Round 7
// 918.749 us; speedup vs baseline: 1.4593x; 1.1180x over previous
//
#include <hip/hip_runtime.h>
#include <math.h>

#define T_STEPS 8192
#define NGROUP  (T_STEPS / 16)   // 512 groups of 16 steps

// hardware transcendentals (v_exp_f32 = 2^x, v_log_f32 = log2 x)
__device__ __forceinline__ float hw_exp2(float x) { return __builtin_amdgcn_exp2f(x); }
__device__ __forceinline__ float hw_log2(float x) { return __builtin_amdgcn_logf(x); }

// DPP add of rotated copy within 16-lane rows. CTRL = 0x120|n (row_ror:n).
template<int CTRL>
__device__ __forceinline__ float dpp_add(float x) {
    int y = __builtin_amdgcn_update_dpp(0, __float_as_int(x), CTRL, 0xF, 0xF, true);
    return x + __int_as_float(y);
}
__device__ __forceinline__ float row16_sum(float x) {
    x = dpp_add<0x128>(x);   // ror:8
    x = dpp_add<0x124>(x);   // ror:4
    x = dpp_add<0x122>(x);   // ror:2
    x = dpp_add<0x121>(x);   // ror:1
    return x;
}

// ---------------------------------------------------------------------------
// Fused FUSE scan. One thread per (ensemble, band); 16 blocks x 64 threads.
// R6 post-mortem: compiler minimizes VGPRs (20!) and sinks forcing loads into
// the body -> ~200cy serial stall per load. Fix: ping-pong register buffers
// whose values are PINNED live via empty asm, placed AFTER the body that the
// loads must overlap. This forces both the allocation and the overlap window.
// ---------------------------------------------------------------------------
__global__ __launch_bounds__(64, 1) void fuse_scan_kernel(
    const float* __restrict__ raw,        // [64][29]
    const float* __restrict__ forcing,    // [8192][3]
    const float* __restrict__ state_init, // [2]
    const float* __restrict__ area_frac,  // [16]
    const float* __restrict__ mean_elev,  // [16]
    float* __restrict__ qout)             // d_out: [64][8192]
{
    const int lane = threadIdx.x;   // 0..63
    const int grp  = lane >> 4;     // ensemble within wave
    const int nb   = lane & 15;     // band
    const int e    = blockIdx.x * 4 + grp;

    const float* rp = raw + e * 29;
    auto phys = [&](int idx, float lo, float hi) {
        float x = rp[idx];
        float s = 1.0f / (1.0f + expf(-x));
        return lo + (hi - lo) * s;
    };
    const float s1max = phys(0,  50.0f,  5000.0f);
    const float s2max = phys(1,  100.0f, 10000.0f);
    const float ku    = phys(6,  0.01f,  1000.0f);
    const float c_exp = phys(7,  1.0f,   20.0f);
    const float ki    = phys(11, 0.01f,  1000.0f);
    const float ks    = phys(12, 0.001f, 10000.0f);
    const float n_exp = phys(13, 1.0f,   10.0f);
    const float acmax = phys(17, 0.05f,  0.95f);
    const float b_exp = phys(18, 0.001f, 3.0f);
    const float train = phys(22, -2.0f,  4.0f);
    const float tmelt = phys(23, -2.0f,  4.0f);
    const float mrate = phys(24, 1.0f,   10.0f);
    const float lapse = phys(25, -9.8f,  0.0f);
    const float opg   = phys(26, 0.0f,   1.0f);

    const float delev  = (mean_elev[nb] - 1500.0f) / 1000.0f;
    const float tshift = lapse * delev;
    const float pmult  = fmaxf(1.0f + opg * delev, 0.0f);
    const float af     = area_frac[nb];
    const float inv_s1max = 1.0f / s1max;
    const float inv_s2max = 1.0f / s2max;

    float swe = 0.0f;
    float s1  = state_init[0];   // invariant: s1 in [0, s1max]
    float s2  = state_init[1];   // 250; >= 0 after first clamp

    float* __restrict__ out = qout + (size_t)e * T_STEPS;
    const float4* __restrict__ fvec = (const float4*)forcing;  // 12 float4 / group

    float fa[48], fb[48];

    auto load_group = [&](float (&f)[48], int g) {
        const int base = g * 12;
        #pragma unroll
        for (int i = 0; i < 12; ++i) {
            const float4 L = fvec[base + i];
            f[4*i+0] = L.x; f[4*i+1] = L.y; f[4*i+2] = L.z; f[4*i+3] = L.w;
        }
    };
    // Force every element of f to be materialized in a VGPR at this point.
    auto pin_group = [&](float (&f)[48]) {
        #pragma unroll
        for (int i = 0; i < 48; ++i) asm volatile("" : "+v"(f[i]));
    };

    auto do_group = [&](const float (&f)[48], int t0) {
        float qkeep = 0.0f;
        #pragma unroll
        for (int tt = 0; tt < 16; ++tt) {
            const float p    = f[3*tt + 0];
            const float pet  = f[3*tt + 1];
            const float tair = f[3*tt + 2];

            // snow bucket (algebraically identical to reference)
            const float tb   = tair + tshift;
            const float pb   = p * pmult;
            const float snow = (tb > train) ? 0.0f : pb;
            const float ssn  = swe + snow;
            const float mcap = mrate * fmaxf(tb - tmelt, 0.0f);
            const float swen = fmaxf(ssn - mcap, 0.0f);
            const float infl = pb + swe - swen;              // rain + melt
            swe = swen;

            // upper bucket; state path after exp is fma->min->max only
            const float w1   = s1 * inv_s1max;               // in [0,1]
            const float lg   = hw_log2(w1);                  // log2(0)=-inf ok
            const float pwb  = hw_exp2(b_exp * lg);          // w1^b
            const float pwc  = hw_exp2(c_exp * lg);          // w1^c
            const float qif  = ki * w1;
            const float pre  = fmaf(-(pet + ki), w1, s1 + infl); // s1+infl-evap-qif
            const float perc = ku * pwc;
            const float qsx  = (acmax * infl) * pwb;
            const float s1n  = pre - (qsx + perc);
            const float sHi  = fminf(s1n, s1max);
            const float over1 = s1n - sHi;
            s1 = fmaxf(sHi, 0.0f);
            const float qsurf = qsx + over1;

            // per-ensemble band sums (16-lane DPP butterflies)
            const float r1 = row16_sum(af * perc);           // rech
            const float r2 = row16_sum(af * (qsurf + qif));  // surface q

            // lower bucket (replicated across the 16-lane row)
            const float w2   = fminf(s2 * inv_s2max, 1.0f);
            const float pw2  = hw_exp2(n_exp * hw_log2(w2)); // w2^n
            const float qb   = ks * pw2;
            const float pre2 = s2 + r1;
            const float s2n  = fmaf(-ks, pw2, pre2);
            const float s2Hi = fminf(s2n, s2max);
            const float over2 = s2n - s2Hi;
            s2 = fmaxf(s2Hi, 0.0f);

            const float q = r2 + qb + over2;
            qkeep = (tt == nb) ? q : qkeep;                  // lane nb keeps t0+nb
        }
        out[t0 + nb] = qkeep;                                // one coalesced store
    };

    load_group(fa, 0);
    pin_group(fa);

    for (int g = 0; g < NGROUP; g += 2) {
        const int g1 = g + 1;                                // <= NGROUP-1 (even NGROUP)
        const int g2 = (g + 2 < NGROUP) ? (g + 2) : (NGROUP - 1);

        load_group(fb, g1);          // issue loads for next group
        do_group(fa, g * 16);        // compute current group (overlap window)
        pin_group(fb);               // wait point AFTER the body

        load_group(fa, g2);
        do_group(fb, g1 * 16);
        pin_group(fa);
    }
}

// ---------------------------------------------------------------------------
// Route: gamma unit-hydrograph, 30-tap causal FIR along time. In-place on
// d_out (full row staged in LDS before any write).
// ---------------------------------------------------------------------------
__global__ __launch_bounds__(256) void route_kernel(
    const float* __restrict__ raw,     // [64][29]
    float* __restrict__ q_io)          // d_out: in = q, out = routed
{
    __shared__ float w_sh[32];
    __shared__ float row[T_STEPS];     // 32 KB

    const int e   = blockIdx.x;
    const int tid = threadIdx.x;

    const float4* src  = (const float4*)(q_io + (size_t)e * T_STEPS);
    float4*       dst4 = (float4*)row;
    for (int i = tid; i < T_STEPS / 4; i += 256) dst4[i] = src[i];

    if (tid < 32) {
        float x     = raw[e * 29 + 21];                 // mu_t raw
        float sig   = 1.0f / (1.0f + expf(-x));
        float delay = 0.01f + (5.0f - 0.01f) * sig;
        float wv = 0.0f;
        if (tid < 30) {
            const float tm   = (float)tid + 0.5f;
            const float kk   = 2.5f;
            const float lgam = 0.28468287047291918f;    // lgamma(2.5)
            float lp = (kk - 1.0f) * logf(tm) - tm / delay - lgam - kk * logf(delay);
            wv = expf(lp);
        }
        w_sh[tid] = wv;
    }
    __syncthreads();
    if (tid == 0) {
        float s = 0.0f;
        for (int l = 0; l < 30; ++l) s += w_sh[l];
        w_sh[31] = 1.0f / s;
    }
    __syncthreads();

    float wloc[30];
    const float inv = w_sh[31];
    #pragma unroll
    for (int l = 0; l < 30; ++l) wloc[l] = w_sh[l] * inv;

    float* __restrict__ out = q_io + (size_t)e * T_STEPS;
    for (int t = tid; t < T_STEPS; t += 256) {
        float acc = 0.0f;
        #pragma unroll
        for (int l = 0; l < 30; ++l) {
            const int idx = t - l;
            const float v = (idx >= 0) ? row[idx] : 0.0f;
            acc = fmaf(wloc[l], v, acc);
        }
        out[t] = acc;
    }
}

// ---------------------------------------------------------------------------
extern "C" void kernel_launch(void* const* d_in, const int* in_sizes, int n_in,
                              void* d_out, int out_size, void* d_ws, size_t ws_size,
                              hipStream_t stream) {
    const float* raw        = (const float*)d_in[0];   // (64, 29)
    const float* forcing    = (const float*)d_in[1];   // (8192, 3)
    const float* state_init = (const float*)d_in[2];   // (2,)
    const float* area_frac  = (const float*)d_in[3];   // (16,)
    const float* mean_elev  = (const float*)d_in[4];   // (16,)

    float* out = (float*)d_out;                        // (64, 8192)

    fuse_scan_kernel<<<16, 64, 0, stream>>>(raw, forcing, state_init,
                                            area_frac, mean_elev, out);
    route_kernel<<<64, 256, 0, stream>>>(raw, out);
}

// Round 8
// 516.134 us; speedup vs baseline: 2.5977x; 1.7801x over previous
//
#include <hip/hip_runtime.h>
#include <math.h>

#define T_STEPS 8192
#define GROUP   16
#define NG      (T_STEPS / GROUP)   // 512 groups

// hardware transcendentals (v_exp_f32 = 2^x, v_log_f32 = log2 x)
__device__ __forceinline__ float hw_exp2(float x) { return __builtin_amdgcn_exp2f(x); }
__device__ __forceinline__ float hw_log2(float x) { return __builtin_amdgcn_logf(x); }

// DPP add of rotated copy within 16-lane rows. CTRL = 0x120|n (row_ror:n).
template<int CTRL>
__device__ __forceinline__ float dpp_add(float x) {
    int y = __builtin_amdgcn_update_dpp(0, __float_as_int(x), CTRL, 0xF, 0xF, true);
    return x + __int_as_float(y);
}
__device__ __forceinline__ float row16_sum(float x) {
    x = dpp_add<0x128>(x);   // ror:8
    x = dpp_add<0x124>(x);   // ror:4
    x = dpp_add<0x122>(x);   // ror:2
    x = dpp_add<0x121>(x);   // ror:1
    return x;
}

// ---------------------------------------------------------------------------
// Wave-specialized pipelined FUSE scan. 16 blocks x 192 threads (3 waves).
// wave0: snow bucket -> infl           (swe recurrence)
// wave1: upper bucket -> perc, qs      (s1 recurrence; 3 transcendentals)
// wave2: band sums + lower bucket -> q (s2 recurrence; DPP + 2 trans)
// Stages communicate 16-step groups via double-buffered LDS; one barrier per
// group. Per-step cost = max(stage) ~90cy instead of the fused sum ~287cy.
// ---------------------------------------------------------------------------
__global__ __launch_bounds__(192, 1) void fuse_pipe_kernel(
    const float* __restrict__ raw,        // [64][29]
    const float* __restrict__ forcing,    // [8192][3]
    const float* __restrict__ state_init, // [2]
    const float* __restrict__ area_frac,  // [16]
    const float* __restrict__ mean_elev,  // [16]
    float* __restrict__ qout)             // d_out: [64][8192]
{
    const int tid  = threadIdx.x;
    const int wid  = tid >> 6;      // 0,1,2
    const int lane = tid & 63;
    const int grp  = lane >> 4;     // ensemble within wave
    const int nb   = lane & 15;     // band
    const int e    = blockIdx.x * 4 + grp;

    __shared__ float bufI[2][GROUP][64];    // infl
    __shared__ float bufPet[2][GROUP];      // pet (wave-uniform per step)
    __shared__ float bufP[2][GROUP][64];    // perc
    __shared__ float bufQ[2][GROUP][64];    // qsurf + qif

    const float* rp = raw + e * 29;
    auto phys = [&](int idx, float lo, float hi) {
        float x = rp[idx];
        float s = 1.0f / (1.0f + expf(-x));
        return lo + (hi - lo) * s;
    };
    // All waves hold all params (cheap; avoids divergent preambles).
    const float s1max = phys(0,  50.0f,  5000.0f);
    const float s2max = phys(1,  100.0f, 10000.0f);
    const float ku    = phys(6,  0.01f,  1000.0f);
    const float c_exp = phys(7,  1.0f,   20.0f);
    const float ki    = phys(11, 0.01f,  1000.0f);
    const float ks    = phys(12, 0.001f, 10000.0f);
    const float n_exp = phys(13, 1.0f,   10.0f);
    const float acmax = phys(17, 0.05f,  0.95f);
    const float b_exp = phys(18, 0.001f, 3.0f);
    const float train = phys(22, -2.0f,  4.0f);
    const float tmelt = phys(23, -2.0f,  4.0f);
    const float mrate = phys(24, 1.0f,   10.0f);
    const float lapse = phys(25, -9.8f,  0.0f);
    const float opg   = phys(26, 0.0f,   1.0f);

    const float delev  = (mean_elev[nb] - 1500.0f) / 1000.0f;
    const float tshift = lapse * delev;
    const float pmult  = fmaxf(1.0f + opg * delev, 0.0f);
    const float af     = area_frac[nb];
    const float inv_s1max = 1.0f / s1max;
    const float inv_s2max = 1.0f / s2max;

    float swe = 0.0f;
    float s1  = state_init[0];
    float s2  = state_init[1];

    float* __restrict__ out = qout + (size_t)e * T_STEPS;
    const float4* __restrict__ fvec = (const float4*)forcing;  // 12 float4/group

    for (int i = 0; i < NG + 2; ++i) {
        if (wid == 0) {
            // ---- stage A: snow bucket, group i ----
            if (i < NG) {
                const int pb_ = i & 1;
                float f[48];
                const int base = i * 12;
                #pragma unroll
                for (int j = 0; j < 12; ++j) {
                    const float4 L = fvec[base + j];
                    f[4*j+0] = L.x; f[4*j+1] = L.y; f[4*j+2] = L.z; f[4*j+3] = L.w;
                }
                #pragma unroll
                for (int tt = 0; tt < GROUP; ++tt) {
                    const float p    = f[3*tt + 0];
                    const float tair = f[3*tt + 2];
                    const float tb   = tair + tshift;
                    const float pcp  = p * pmult;
                    const float snow = (tb > train) ? 0.0f : pcp;
                    const float ssn  = swe + snow;
                    const float mcap = mrate * fmaxf(tb - tmelt, 0.0f);
                    const float swen = fmaxf(ssn - mcap, 0.0f);
                    const float infl = pcp + swe - swen;     // rain + melt
                    swe = swen;
                    bufI[pb_][tt][lane] = infl;
                }
                if (lane == 0) {
                    #pragma unroll
                    for (int tt = 0; tt < GROUP; ++tt)
                        bufPet[pb_][tt] = f[3*tt + 1];
                }
            }
        } else if (wid == 1) {
            // ---- stage B: upper bucket, group i-1 ----
            const int g = i - 1;
            if (g >= 0 && g < NG) {
                const int pb_ = g & 1;
                float inflr[GROUP], petr[GROUP];
                #pragma unroll
                for (int tt = 0; tt < GROUP; ++tt) {
                    inflr[tt] = bufI[pb_][tt][lane];
                    petr[tt]  = bufPet[pb_][tt];
                }
                #pragma unroll
                for (int tt = 0; tt < GROUP; ++tt)
                    asm volatile("" : "+v"(inflr[tt]), "+v"(petr[tt]));

                #pragma unroll
                for (int tt = 0; tt < GROUP; ++tt) {
                    const float infl = inflr[tt], pet = petr[tt];
                    const float w1   = s1 * inv_s1max;       // in [0,1]
                    const float lg   = hw_log2(w1);          // log2(0)=-inf ok
                    const float pwb  = hw_exp2(b_exp * lg);  // w1^b
                    const float pwc  = hw_exp2(c_exp * lg);  // w1^c
                    const float perc = ku * pwc;
                    const float qif  = ki * w1;
                    const float pre  = fmaf(-(pet + ki), w1, s1 + infl);
                    const float qsx  = (acmax * infl) * pwb;
                    const float s1n  = pre - (qsx + perc);
                    const float sHi  = fminf(s1n, s1max);
                    const float over1 = s1n - sHi;
                    s1 = fmaxf(sHi, 0.0f);
                    const float qsurf = qsx + over1;
                    bufP[pb_][tt][lane] = perc;
                    bufQ[pb_][tt][lane] = qsurf + qif;
                }
            }
        } else {
            // ---- stage C: band sums + lower bucket + q, group i-2 ----
            const int g = i - 2;
            if (g >= 0) {
                const int pb_ = g & 1;
                float pr[GROUP], qr[GROUP];
                #pragma unroll
                for (int tt = 0; tt < GROUP; ++tt) {
                    pr[tt] = bufP[pb_][tt][lane];
                    qr[tt] = bufQ[pb_][tt][lane];
                }
                #pragma unroll
                for (int tt = 0; tt < GROUP; ++tt)
                    asm volatile("" : "+v"(pr[tt]), "+v"(qr[tt]));

                float qkeep = 0.0f;
                #pragma unroll
                for (int tt = 0; tt < GROUP; ++tt) {
                    const float r1 = row16_sum(af * pr[tt]);   // rech
                    const float r2 = row16_sum(af * qr[tt]);   // surface q
                    const float w2   = fminf(s2 * inv_s2max, 1.0f);
                    const float pw2  = hw_exp2(n_exp * hw_log2(w2)); // w2^n
                    const float qb   = ks * pw2;
                    const float s2n  = fmaf(-ks, pw2, s2 + r1);
                    const float s2Hi = fminf(s2n, s2max);
                    const float over2 = s2n - s2Hi;
                    s2 = fmaxf(s2Hi, 0.0f);
                    const float q = r2 + qb + over2;
                    qkeep = (tt == nb) ? q : qkeep;
                }
                out[g * GROUP + nb] = qkeep;     // coalesced, 16 t per group
            }
        }
        __syncthreads();
    }
}

// ---------------------------------------------------------------------------
// Route: gamma unit-hydrograph, 30-tap causal FIR along time. In-place on
// d_out (full row staged in LDS before any write).
// ---------------------------------------------------------------------------
__global__ __launch_bounds__(256) void route_kernel(
    const float* __restrict__ raw,     // [64][29]
    float* __restrict__ q_io)          // d_out: in = q, out = routed
{
    __shared__ float w_sh[32];
    __shared__ float row[T_STEPS];     // 32 KB

    const int e   = blockIdx.x;
    const int tid = threadIdx.x;

    const float4* src  = (const float4*)(q_io + (size_t)e * T_STEPS);
    float4*       dst4 = (float4*)row;
    for (int i = tid; i < T_STEPS / 4; i += 256) dst4[i] = src[i];

    if (tid < 32) {
        float x     = raw[e * 29 + 21];                 // mu_t raw
        float sig   = 1.0f / (1.0f + expf(-x));
        float delay = 0.01f + (5.0f - 0.01f) * sig;
        float wv = 0.0f;
        if (tid < 30) {
            const float tm   = (float)tid + 0.5f;
            const float kk   = 2.5f;
            const float lgam = 0.28468287047291918f;    // lgamma(2.5)
            float lp = (kk - 1.0f) * logf(tm) - tm / delay - lgam - kk * logf(delay);
            wv = expf(lp);
        }
        w_sh[tid] = wv;
    }
    __syncthreads();
    if (tid == 0) {
        float s = 0.0f;
        for (int l = 0; l < 30; ++l) s += w_sh[l];
        w_sh[31] = 1.0f / s;
    }
    __syncthreads();

    float wloc[30];
    const float inv = w_sh[31];
    #pragma unroll
    for (int l = 0; l < 30; ++l) wloc[l] = w_sh[l] * inv;

    float* __restrict__ out = q_io + (size_t)e * T_STEPS;
    for (int t = tid; t < T_STEPS; t += 256) {
        float acc = 0.0f;
        #pragma unroll
        for (int l = 0; l < 30; ++l) {
            const int idx = t - l;
            const float v = (idx >= 0) ? row[idx] : 0.0f;
            acc = fmaf(wloc[l], v, acc);
        }
        out[t] = acc;
    }
}

// ---------------------------------------------------------------------------
extern "C" void kernel_launch(void* const* d_in, const int* in_sizes, int n_in,
                              void* d_out, int out_size, void* d_ws, size_t ws_size,
                              hipStream_t stream) {
    const float* raw        = (const float*)d_in[0];   // (64, 29)
    const float* forcing    = (const float*)d_in[1];   // (8192, 3)
    const float* state_init = (const float*)d_in[2];   // (2,)
    const float* area_frac  = (const float*)d_in[3];   // (16,)
    const float* mean_elev  = (const float*)d_in[4];   // (16,)

    float* out = (float*)d_out;                        // (64, 8192)

    fuse_pipe_kernel<<<16, 192, 0, stream>>>(raw, forcing, state_init,
                                             area_frac, mean_elev, out);
    route_kernel<<<64, 256, 0, stream>>>(raw, out);
}

// Round 9
// 450.592 us; speedup vs baseline: 2.9756x; 1.1455x over previous
//
#include <hip/hip_runtime.h>
#include <math.h>

#define T_STEPS 8192
#define GROUP   32
#define NG      (T_STEPS / GROUP)   // 256 groups

// hardware transcendentals (v_exp_f32 = 2^x, v_log_f32 = log2 x)
__device__ __forceinline__ float hw_exp2(float x) { return __builtin_amdgcn_exp2f(x); }
__device__ __forceinline__ float hw_log2(float x) { return __builtin_amdgcn_logf(x); }

// DPP add of rotated copy within 16-lane rows. CTRL = 0x120|n (row_ror:n).
template<int CTRL>
__device__ __forceinline__ float dpp_add(float x) {
    int y = __builtin_amdgcn_update_dpp(0, __float_as_int(x), CTRL, 0xF, 0xF, true);
    return x + __int_as_float(y);
}
__device__ __forceinline__ float row16_sum(float x) {
    x = dpp_add<0x128>(x);   // ror:8
    x = dpp_add<0x124>(x);   // ror:4
    x = dpp_add<0x122>(x);   // ror:2
    x = dpp_add<0x121>(x);   // ror:1
    return x;
}

// ---------------------------------------------------------------------------
// Wave-specialized pipelined FUSE scan. 16 blocks x 192 threads (3 waves).
//   wave0 (A): snow bucket -> infl, ai=acmax*infl, cm=1-(pet+ki)/s1max
//   wave1 (B): s1 recurrence -> af*perc, af*(qsurf+qif)
//   wave2 (C): 16-band DPP sums + s2 recurrence -> q
// GROUP=32 halves the per-group handoff overhead vs R8 (barriers, LDS head
// latency, waitcnt drains). Double-buffered LDS, one barrier per group.
// ---------------------------------------------------------------------------
__global__ __launch_bounds__(192, 1) void fuse_pipe_kernel(
    const float* __restrict__ raw,        // [64][29]
    const float* __restrict__ forcing,    // [8192][3]
    const float* __restrict__ state_init, // [2]
    const float* __restrict__ area_frac,  // [16]
    const float* __restrict__ mean_elev,  // [16]
    float* __restrict__ qout)             // d_out: [64][8192]
{
    const int tid  = threadIdx.x;
    const int wid  = tid >> 6;      // 0,1,2
    const int lane = tid & 63;
    const int grp  = lane >> 4;     // ensemble within wave
    const int nb   = lane & 15;     // band
    const int e    = blockIdx.x * 4 + grp;

    __shared__ float bufI[2][GROUP][64];   // infl
    __shared__ float bufA[2][GROUP][64];   // acmax*infl
    __shared__ float bufC[2][GROUP][64];   // 1-(pet+ki)*inv_s1max
    __shared__ float bufP[2][GROUP][64];   // af*perc
    __shared__ float bufQ[2][GROUP][64];   // af*(qsurf+qif)
    // total LDS = 5*2*32*64*4 = 80 KB

    const float* rp = raw + e * 29;
    auto phys = [&](int idx, float lo, float hi) {
        float x = rp[idx];
        float s = 1.0f / (1.0f + expf(-x));
        return lo + (hi - lo) * s;
    };
    const float s1max = phys(0,  50.0f,  5000.0f);
    const float s2max = phys(1,  100.0f, 10000.0f);
    const float ku    = phys(6,  0.01f,  1000.0f);
    const float c_exp = phys(7,  1.0f,   20.0f);
    const float ki    = phys(11, 0.01f,  1000.0f);
    const float ks    = phys(12, 0.001f, 10000.0f);
    const float n_exp = phys(13, 1.0f,   10.0f);
    const float acmax = phys(17, 0.05f,  0.95f);
    const float b_exp = phys(18, 0.001f, 3.0f);
    const float train = phys(22, -2.0f,  4.0f);
    const float tmelt = phys(23, -2.0f,  4.0f);
    const float mrate = phys(24, 1.0f,   10.0f);
    const float lapse = phys(25, -9.8f,  0.0f);
    const float opg   = phys(26, 0.0f,   1.0f);

    const float delev  = (mean_elev[nb] - 1500.0f) / 1000.0f;
    const float tshift = lapse * delev;
    const float pmult  = fmaxf(1.0f + opg * delev, 0.0f);
    const float af     = area_frac[nb];
    const float inv_s1max = 1.0f / s1max;
    const float inv_s2max = 1.0f / s2max;
    const float afku   = af * ku;

    float swe = 0.0f;
    float s1  = state_init[0];
    float s2  = state_init[1];

    float* __restrict__ out = qout + (size_t)e * T_STEPS;
    const float4* __restrict__ fvec = (const float4*)forcing;  // 24 float4/group

    for (int i = 0; i < NG + 2; ++i) {
        if (wid == 0) {
            // ---- stage A: snow bucket + per-step precomputation, group i ----
            if (i < NG) {
                const int pb_ = i & 1;
                float f[96];
                const int base = i * 24;
                #pragma unroll
                for (int j = 0; j < 24; ++j) {
                    const float4 L = fvec[base + j];
                    f[4*j+0] = L.x; f[4*j+1] = L.y; f[4*j+2] = L.z; f[4*j+3] = L.w;
                }
                #pragma unroll
                for (int tt = 0; tt < GROUP; ++tt) {
                    const float p    = f[3*tt + 0];
                    const float pet  = f[3*tt + 1];
                    const float tair = f[3*tt + 2];
                    const float tb   = tair + tshift;
                    const float pcp  = p * pmult;
                    const float snow = (tb > train) ? 0.0f : pcp;
                    const float ssn  = swe + snow;
                    const float mcap = mrate * fmaxf(tb - tmelt, 0.0f);
                    const float swen = fmaxf(ssn - mcap, 0.0f);
                    const float infl = pcp + swe - swen;        // rain + melt
                    swe = swen;
                    bufI[pb_][tt][lane] = infl;
                    bufA[pb_][tt][lane] = acmax * infl;
                    bufC[pb_][tt][lane] = fmaf(-(pet + ki), inv_s1max, 1.0f);
                }
            }
        } else if (wid == 1) {
            // ---- stage B: upper-bucket (s1) recurrence, group i-1 ----
            const int g = i - 1;
            if (g >= 0 && g < NG) {
                const int pb_ = g & 1;
                float fi[GROUP], fa[GROUP], fc[GROUP];
                #pragma unroll
                for (int tt = 0; tt < GROUP; ++tt) {
                    fi[tt] = bufI[pb_][tt][lane];
                    fa[tt] = bufA[pb_][tt][lane];
                    fc[tt] = bufC[pb_][tt][lane];
                }
                #pragma unroll
                for (int tt = 0; tt < GROUP; ++tt)
                    asm volatile("" : "+v"(fi[tt]), "+v"(fa[tt]), "+v"(fc[tt]));

                #pragma unroll
                for (int tt = 0; tt < GROUP; ++tt) {
                    const float w1   = s1 * inv_s1max;          // in [0,1]
                    const float lg   = hw_log2(w1);             // log2(0)=-inf ok
                    const float pwb  = hw_exp2(b_exp * lg);     // w1^b
                    const float pwc  = hw_exp2(c_exp * lg);     // w1^c
                    const float pre  = fmaf(fc[tt], s1, fi[tt]); // s1+infl-evap-qif
                    const float qsx  = fa[tt] * pwb;            // acmax*infl*w1^b
                    const float t1   = fmaf(-ku, pwc, pre);     // ... - perc
                    const float s1n  = t1 - qsx;
                    const float sHi  = fminf(s1n, s1max);
                    const float over1 = s1n - sHi;
                    s1 = fmaxf(sHi, 0.0f);
                    const float qif  = ki * w1;
                    bufP[pb_][tt][lane] = afku * pwc;           // af*perc
                    bufQ[pb_][tt][lane] = af * ((qsx + over1) + qif);
                }
            }
        } else {
            // ---- stage C: band sums + lower-bucket (s2) recurrence, group i-2 ----
            const int g = i - 2;
            if (g >= 0) {
                const int pb_ = g & 1;
                float pr[GROUP], qr[GROUP];
                #pragma unroll
                for (int tt = 0; tt < GROUP; ++tt) {
                    pr[tt] = bufP[pb_][tt][lane];
                    qr[tt] = bufQ[pb_][tt][lane];
                }
                #pragma unroll
                for (int tt = 0; tt < GROUP; ++tt)
                    asm volatile("" : "+v"(pr[tt]), "+v"(qr[tt]));

                // all 32 band-sums up front (off-recurrence; scheduler can
                // slot these into s2-chain stall cycles)
                #pragma unroll
                for (int tt = 0; tt < GROUP; ++tt) {
                    pr[tt] = row16_sum(pr[tt]);    // rech
                    qr[tt] = row16_sum(qr[tt]);    // surface q
                }

                float qk0 = 0.0f, qk1 = 0.0f;
                #pragma unroll
                for (int tt = 0; tt < GROUP; ++tt) {
                    const float w2r = s2 * inv_s2max;            // >1 only at t=0
                    const float lg2 = hw_log2(w2r);              // log2(0)=-inf ok
                    const float pw  = hw_exp2(n_exp * lg2);      // w2r^n
                    const float pwm = fminf(pw, 1.0f);           // == clip(w2r)^n
                    const float qb  = ks * pwm;
                    const float s2n = fmaf(-ks, pwm, s2 + pr[tt]);
                    const float sHi = fminf(s2n, s2max);
                    const float over2 = s2n - sHi;
                    s2 = fmaxf(sHi, 0.0f);
                    const float q = qr[tt] + qb + over2;
                    if (tt < 16) qk0 = (tt == nb) ? q : qk0;
                    else         qk1 = ((tt - 16) == nb) ? q : qk1;
                }
                float* __restrict__ o = out + g * GROUP;
                o[nb]      = qk0;                 // coalesced 16-wide
                o[nb + 16] = qk1;
            }
        }
        __syncthreads();
    }
}

// ---------------------------------------------------------------------------
// Route: gamma unit-hydrograph, 30-tap causal FIR along time. In-place on
// d_out (full row staged in LDS before any write).
// ---------------------------------------------------------------------------
__global__ __launch_bounds__(256) void route_kernel(
    const float* __restrict__ raw,     // [64][29]
    float* __restrict__ q_io)          // d_out: in = q, out = routed
{
    __shared__ float w_sh[32];
    __shared__ float row[T_STEPS];     // 32 KB

    const int e   = blockIdx.x;
    const int tid = threadIdx.x;

    const float4* src  = (const float4*)(q_io + (size_t)e * T_STEPS);
    float4*       dst4 = (float4*)row;
    for (int i = tid; i < T_STEPS / 4; i += 256) dst4[i] = src[i];

    if (tid < 32) {
        float x     = raw[e * 29 + 21];                 // mu_t raw
        float sig   = 1.0f / (1.0f + expf(-x));
        float delay = 0.01f + (5.0f - 0.01f) * sig;
        float wv = 0.0f;
        if (tid < 30) {
            const float tm   = (float)tid + 0.5f;
            const float kk   = 2.5f;
            const float lgam = 0.28468287047291918f;    // lgamma(2.5)
            float lp = (kk - 1.0f) * logf(tm) - tm / delay - lgam - kk * logf(delay);
            wv = expf(lp);
        }
        w_sh[tid] = wv;
    }
    __syncthreads();
    if (tid == 0) {
        float s = 0.0f;
        for (int l = 0; l < 30; ++l) s += w_sh[l];
        w_sh[31] = 1.0f / s;
    }
    __syncthreads();

    float wloc[30];
    const float inv = w_sh[31];
    #pragma unroll
    for (int l = 0; l < 30; ++l) wloc[l] = w_sh[l] * inv;

    float* __restrict__ out = q_io + (size_t)e * T_STEPS;
    for (int t = tid; t < T_STEPS; t += 256) {
        float acc = 0.0f;
        #pragma unroll
        for (int l = 0; l < 30; ++l) {
            const int idx = t - l;
            const float v = (idx >= 0) ? row[idx] : 0.0f;
            acc = fmaf(wloc[l], v, acc);
        }
        out[t] = acc;
    }
}

// ---------------------------------------------------------------------------
extern "C" void kernel_launch(void* const* d_in, const int* in_sizes, int n_in,
                              void* d_out, int out_size, void* d_ws, size_t ws_size,
                              hipStream_t stream) {
    const float* raw        = (const float*)d_in[0];   // (64, 29)
    const float* forcing    = (const float*)d_in[1];   // (8192, 3)
    const float* state_init = (const float*)d_in[2];   // (2,)
    const float* area_frac  = (const float*)d_in[3];   // (16,)
    const float* mean_elev  = (const float*)d_in[4];   // (16,)

    float* out = (float*)d_out;                        // (64, 8192)

    fuse_pipe_kernel<<<16, 192, 0, stream>>>(raw, forcing, state_init,
                                             area_frac, mean_elev, out);
    route_kernel<<<64, 256, 0, stream>>>(raw, out);
}